// Round 1
// baseline (143.577 us; speedup 1.0000x reference)
//
#include <hip/hip_runtime.h>
#include <math.h>

// out[b,i,j,f] = min_{di,dj,c} ( x[b,i+di,j+dj,c] - W[di,dj,c,f] )
// x: (16,128,128,16) f32, W: (3,3,16,32) f32, out: (16,126,126,32) f32
//
// Mapping: block = 256 threads = 4 output columns x 32 f x 2 c-halves.
//   tid bits: f = tid&31, ch = (tid>>5)&1 (c-half), jt = tid>>6 (column, wave-uniform)
// Each thread: fixed (j, f, c-half); W slice (9 pos x 8 c) in VGPRs; slides a
// 3-row rolling min accumulator down TI output rows, loading each x row once
// (6 dwordx4). c-halves merged with one __shfl_xor(32) per output.

#define TI 21  // output rows per block; 126 = 21*6

__device__ __forceinline__ float min3f(float a, float b, float c) {
    return fminf(fminf(a, b), c);  // expect v_min3_f32
}

__device__ __forceinline__ float redmin24(const float* t) {
    float m[8];
#pragma unroll
    for (int k = 0; k < 8; ++k) m[k] = min3f(t[3*k], t[3*k+1], t[3*k+2]);
    return min3f(min3f(m[0], m[1], m[2]),
                 min3f(m[3], m[4], m[5]),
                 fminf(m[6], m[7]));
}

__global__ __launch_bounds__(256) void erosion_kernel(
    const float* __restrict__ x, const float* __restrict__ Wt,
    float* __restrict__ out)
{
    const int tid = threadIdx.x;
    const int f  = tid & 31;
    const int ch = (tid >> 5) & 1;   // channel half: 0 -> c 0..7, 1 -> c 8..15
    const int jt = tid >> 6;         // column in block (wave-uniform)
    const int b  = blockIdx.z;
    const int i0 = blockIdx.y * TI;
    int j = blockIdx.x * 4 + jt;     // 0..127
    const bool jvalid = (j < 126);
    if (!jvalid) j = 125;            // clamp so loads stay in bounds

    // W slice into registers: w[p][c] = W[p, ch*8+c, f], p = di*3+dj
    float w[9][8];
#pragma unroll
    for (int p = 0; p < 9; ++p)
#pragma unroll
        for (int c = 0; c < 8; ++c)
            w[p][c] = Wt[(p * 16 + ch * 8 + c) * 32 + f];

    const float* xb = x + ((size_t)b * 128 * 128 + (size_t)j) * 16 + ch * 8;
    float* op = out + (((size_t)b * 126 + i0) * 126 + j) * 32 + f;

    float accB = INFINITY;  // partial min for output row r-1
    float accC = INFINITY;  // partial min for output row r-2

#pragma unroll 1
    for (int r = 0; r < TI + 2; ++r) {
        const float* xr = xb + (size_t)(i0 + r) * 2048;  // 128*16 floats per image row
        float xv[24];
#pragma unroll
        for (int dj = 0; dj < 3; ++dj) {
            float4 lo = *reinterpret_cast<const float4*>(xr + dj * 16);
            float4 hi = *reinterpret_cast<const float4*>(xr + dj * 16 + 4);
            xv[dj*8+0] = lo.x; xv[dj*8+1] = lo.y; xv[dj*8+2] = lo.z; xv[dj*8+3] = lo.w;
            xv[dj*8+4] = hi.x; xv[dj*8+5] = hi.y; xv[dj*8+6] = hi.z; xv[dj*8+7] = hi.w;
        }

        // Input row (i0+r) contributes with weight row di to output row (i0+r-di).
        float n0, n1, n2;
        {
            float t[24];
#pragma unroll
            for (int dj = 0; dj < 3; ++dj)
#pragma unroll
                for (int c = 0; c < 8; ++c)
                    t[dj*8+c] = xv[dj*8+c] - w[0*3+dj][c];
            n0 = redmin24(t);
        }
        {
            float t[24];
#pragma unroll
            for (int dj = 0; dj < 3; ++dj)
#pragma unroll
                for (int c = 0; c < 8; ++c)
                    t[dj*8+c] = xv[dj*8+c] - w[1*3+dj][c];
            n1 = redmin24(t);
        }
        {
            float t[24];
#pragma unroll
            for (int dj = 0; dj < 3; ++dj)
#pragma unroll
                for (int c = 0; c < 8; ++c)
                    t[dj*8+c] = xv[dj*8+c] - w[2*3+dj][c];
            n2 = redmin24(t);
        }

        float fin = fminf(accC, n2);  // output row r-2 complete
        accC = fminf(accB, n1);
        accB = n0;

        if (r >= 2) {
            // merge the two channel halves (lane pairs tid, tid^32)
            fin = fminf(fin, __shfl_xor(fin, 32));
            if (jvalid && ch == 0)
                op[(size_t)(r - 2) * (126 * 32)] = fin;
        }
    }
}

extern "C" void kernel_launch(void* const* d_in, const int* in_sizes, int n_in,
                              void* d_out, int out_size, void* d_ws, size_t ws_size,
                              hipStream_t stream) {
    const float* x  = (const float*)d_in[0];  // 16*128*128*16
    const float* Wt = (const float*)d_in[1];  // 3*3*16*32
    float* out = (float*)d_out;               // 16*126*126*32

    dim3 grid(32, 6, 16);   // 32 j-blocks * (126/TI) row-blocks * 16 batches
    dim3 block(256);
    erosion_kernel<<<grid, block, 0, stream>>>(x, Wt, out);
}

// Round 2
// 129.625 us; speedup vs baseline: 1.1076x; 1.1076x over previous
//
#include <hip/hip_runtime.h>
#include <math.h>

// out[b,i,j,f] = min_{di,dj,c} ( x[b,i+di,j+dj,c] - W[di,dj,c,f] )
// x: (16,128,128,16) f32, W: (3,3,16,32) f32, out: (16,126,126,32) f32
//
// Same verified mapping as R1 (block = 4 cols x 32 f x 2 c-halves, rolling
// 3-row min window down TI output rows), but inner math in PACKED fp16:
// adjacent c-channel pairs live in half2 lanes -> v_pk_add_f16(neg)/v_pk_min_f16
// halve the VALU op count. fp16 error ~1e-2 << 9.75e-2 threshold.

#define TI 21  // output rows per block; 126 = 21*6

typedef _Float16 h2 __attribute__((ext_vector_type(2)));

__device__ __forceinline__ h2 hmin2(h2 a, h2 b) {
    return __builtin_elementwise_min(a, b);  // v_pk_min_f16
}

__device__ __forceinline__ h2 pkrtz(float a, float b) {
    auto r = __builtin_amdgcn_cvt_pkrtz(a, b);  // v_cvt_pkrtz_f16_f32
    return *reinterpret_cast<h2*>(&r);
}

// min over 12 half2 values of (hx[k] - w[k]) for one weight row di
__device__ __forceinline__ h2 rowmin(const h2* hx, const h2 w[3][4]) {
    h2 t[12];
#pragma unroll
    for (int dj = 0; dj < 3; ++dj)
#pragma unroll
        for (int q = 0; q < 4; ++q)
            t[dj * 4 + q] = hx[dj * 4 + q] - w[dj][q];  // v_pk_add_f16 neg
#pragma unroll
    for (int k = 0; k < 6; ++k) t[k] = hmin2(t[k], t[k + 6]);
    t[0] = hmin2(t[0], t[3]);
    t[1] = hmin2(t[1], t[4]);
    t[2] = hmin2(t[2], t[5]);
    return hmin2(hmin2(t[0], t[1]), t[2]);
}

__global__ __launch_bounds__(256) void erosion_kernel(
    const float* __restrict__ x, const float* __restrict__ Wt,
    float* __restrict__ out)
{
    const int tid = threadIdx.x;
    const int f  = tid & 31;
    const int ch = (tid >> 5) & 1;   // channel half: 0 -> c 0..7, 1 -> c 8..15
    const int jt = tid >> 6;         // column in block (wave-uniform)
    const int b  = blockIdx.z;
    const int i0 = blockIdx.y * TI;
    int j = blockIdx.x * 4 + jt;     // 0..127
    const bool jvalid = (j < 126);
    if (!jvalid) j = 125;            // clamp so loads stay in bounds

    // W slice in registers as fp16 pairs:
    // wh[di][dj][q] = { W[di,dj, C, f], W[di,dj, C+1, f] },  C = ch*8 + 2q
    h2 wh[3][3][4];
#pragma unroll
    for (int di = 0; di < 3; ++di)
#pragma unroll
        for (int dj = 0; dj < 3; ++dj)
#pragma unroll
            for (int q = 0; q < 4; ++q) {
                int p = di * 3 + dj;
                float a = Wt[(p * 16 + ch * 8 + 2 * q) * 32 + f];
                float c = Wt[(p * 16 + ch * 8 + 2 * q + 1) * 32 + f];
                wh[di][dj][q] = pkrtz(a, c);
            }

    const float* xb = x + ((size_t)b * 128 * 128 + (size_t)j) * 16 + ch * 8;
    float* op = out + (((size_t)b * 126 + i0) * 126 + j) * 32 + f;

    const _Float16 HINF = (_Float16)__builtin_huge_valf();
    h2 accB = {HINF, HINF};  // partial min for output row r-1
    h2 accC = {HINF, HINF};  // partial min for output row r-2

#pragma unroll 1
    for (int r = 0; r < TI + 2; ++r) {
        const float* xr = xb + (size_t)(i0 + r) * 2048;  // 128*16 floats/row
        h2 hx[12];
#pragma unroll
        for (int dj = 0; dj < 3; ++dj) {
            float4 lo = *reinterpret_cast<const float4*>(xr + dj * 16);
            float4 hi = *reinterpret_cast<const float4*>(xr + dj * 16 + 4);
            hx[dj * 4 + 0] = pkrtz(lo.x, lo.y);
            hx[dj * 4 + 1] = pkrtz(lo.z, lo.w);
            hx[dj * 4 + 2] = pkrtz(hi.x, hi.y);
            hx[dj * 4 + 3] = pkrtz(hi.z, hi.w);
        }

        // Input row (i0+r) contributes with weight row di to output row (i0+r-di)
        h2 n0 = rowmin(hx, wh[0]);
        h2 n1 = rowmin(hx, wh[1]);
        h2 n2 = rowmin(hx, wh[2]);

        h2 fin2 = hmin2(accC, n2);  // output row r-2 complete
        accC = hmin2(accB, n1);
        accB = n0;

        if (r >= 2) {
            float v = fminf((float)fin2[0], (float)fin2[1]);
            // merge the two channel halves (lane pairs tid, tid^32)
            v = fminf(v, __shfl_xor(v, 32));
            if (jvalid && ch == 0)
                op[(size_t)(r - 2) * (126 * 32)] = v;
        }
    }
}

extern "C" void kernel_launch(void* const* d_in, const int* in_sizes, int n_in,
                              void* d_out, int out_size, void* d_ws, size_t ws_size,
                              hipStream_t stream) {
    const float* x  = (const float*)d_in[0];  // 16*128*128*16
    const float* Wt = (const float*)d_in[1];  // 3*3*16*32
    float* out = (float*)d_out;               // 16*126*126*32

    dim3 grid(32, 6, 16);   // 32 j-blocks * (126/TI) row-blocks * 16 batches
    dim3 block(256);
    erosion_kernel<<<grid, block, 0, stream>>>(x, Wt, out);
}

// Round 3
// 118.546 us; speedup vs baseline: 1.2112x; 1.0935x over previous
//
#include <hip/hip_runtime.h>
#include <math.h>

// out[b,i,j,f] = min_{di,dj,c} ( x[b,i+di,j+dj,c] - W[di,dj,c,f] )
// x: (16,128,128,16) f32, W: (3,3,16,32) f32, out: (16,126,126,32) f32
//
// R3: pre-convert x to fp16 in d_ws (one cheap memory-bound pass), so the
// hot loop loads ready-packed fp16 (3 dwordx4/iter, no cvt). Row loop
// unrolled 2x for cross-row load/math overlap. Math stays packed fp16
// (v_pk_add_f16 neg + v_pk_min_f16), 72 math insts per wave-iter.

#define TI 21  // output rows per block; 126 = 21*6

typedef _Float16 h2 __attribute__((ext_vector_type(2)));

__device__ __forceinline__ h2 hmin2(h2 a, h2 b) {
    return __builtin_elementwise_min(a, b);  // v_pk_min_f16
}

__device__ __forceinline__ h2 pkrtz(float a, float b) {
    auto r = __builtin_amdgcn_cvt_pkrtz(a, b);  // v_cvt_pkrtz_f16_f32
    return *reinterpret_cast<h2*>(&r);
}

// min over 12 half2 of (hx[k] - w[k]) for one weight row di
__device__ __forceinline__ h2 rowmin(const h2* hx, const h2 w[3][4]) {
    h2 t[12];
#pragma unroll
    for (int dj = 0; dj < 3; ++dj)
#pragma unroll
        for (int q = 0; q < 4; ++q)
            t[dj * 4 + q] = hx[dj * 4 + q] - w[dj][q];  // v_pk_add_f16 neg
#pragma unroll
    for (int k = 0; k < 6; ++k) t[k] = hmin2(t[k], t[k + 6]);
    t[0] = hmin2(t[0], t[3]);
    t[1] = hmin2(t[1], t[4]);
    t[2] = hmin2(t[2], t[5]);
    return hmin2(hmin2(t[0], t[1]), t[2]);
}

// ---- pre-pass: x fp32 -> fp16, same layout ----
__global__ __launch_bounds__(256) void cvt_kernel(const float* __restrict__ x,
                                                  _Float16* __restrict__ xh) {
    int idx = (blockIdx.x * 256 + threadIdx.x) * 8;
    float4 a = *reinterpret_cast<const float4*>(x + idx);
    float4 b = *reinterpret_cast<const float4*>(x + idx + 4);
    h2 o[4] = { pkrtz(a.x, a.y), pkrtz(a.z, a.w), pkrtz(b.x, b.y), pkrtz(b.z, b.w) };
    *reinterpret_cast<float4*>(xh + idx) = *reinterpret_cast<float4*>(o);
}

// ---- main kernel, fp16 pre-converted input ----
__global__ __launch_bounds__(256) void erosion_h_kernel(
    const _Float16* __restrict__ xh, const float* __restrict__ Wt,
    float* __restrict__ out)
{
    const int tid = threadIdx.x;
    const int f  = tid & 31;
    const int ch = (tid >> 5) & 1;   // channel half: 0 -> c 0..7, 1 -> c 8..15
    const int jt = tid >> 6;         // column in block (wave-uniform)
    const int b  = blockIdx.z;
    const int i0 = blockIdx.y * TI;
    int j = blockIdx.x * 4 + jt;     // 0..127
    const bool jvalid = (j < 126);
    if (!jvalid) j = 125;            // clamp so loads stay in bounds

    // wh[di][dj][q] = { W[di,dj, ch*8+2q, f], W[di,dj, ch*8+2q+1, f] } as fp16
    h2 wh[3][3][4];
#pragma unroll
    for (int di = 0; di < 3; ++di)
#pragma unroll
        for (int dj = 0; dj < 3; ++dj)
#pragma unroll
            for (int q = 0; q < 4; ++q) {
                int p = di * 3 + dj;
                float a = Wt[(p * 16 + ch * 8 + 2 * q) * 32 + f];
                float c = Wt[(p * 16 + ch * 8 + 2 * q + 1) * 32 + f];
                wh[di][dj][q] = pkrtz(a, c);
            }

    const _Float16* xb = xh + ((size_t)b * 128 * 128 + (size_t)j) * 16 + ch * 8;
    float* op = out + (((size_t)b * 126 + i0) * 126 + j) * 32 + f;

    const _Float16 HINF = (_Float16)__builtin_huge_valf();
    h2 accB = {HINF, HINF};  // partial min for output row r-1
    h2 accC = {HINF, HINF};  // partial min for output row r-2

#pragma unroll 2
    for (int r = 0; r < TI + 2; ++r) {
        const _Float16* xr = xb + (size_t)(i0 + r) * 2048;  // 128*16 halves/row
        h2 hx[12];
#pragma unroll
        for (int dj = 0; dj < 3; ++dj) {
            float4 raw = *reinterpret_cast<const float4*>(xr + dj * 16);
            const h2* p = reinterpret_cast<const h2*>(&raw);
            hx[dj * 4 + 0] = p[0];
            hx[dj * 4 + 1] = p[1];
            hx[dj * 4 + 2] = p[2];
            hx[dj * 4 + 3] = p[3];
        }

        h2 n0 = rowmin(hx, wh[0]);
        h2 n1 = rowmin(hx, wh[1]);
        h2 n2 = rowmin(hx, wh[2]);

        h2 fin2 = hmin2(accC, n2);  // output row r-2 complete
        accC = hmin2(accB, n1);
        accB = n0;

        if (r >= 2) {
            _Float16 vm = fin2[0] < fin2[1] ? fin2[0] : fin2[1];  // v_min_f16
            float v = (float)vm;
            v = fminf(v, __shfl_xor(v, 32));  // merge c-halves (lanes tid, tid^32)
            if (jvalid && ch == 0)
                op[(size_t)(r - 2) * (126 * 32)] = v;
        }
    }
}

// ---- fallback (ws too small): R2-style in-kernel conversion ----
__global__ __launch_bounds__(256) void erosion_kernel(
    const float* __restrict__ x, const float* __restrict__ Wt,
    float* __restrict__ out)
{
    const int tid = threadIdx.x;
    const int f  = tid & 31;
    const int ch = (tid >> 5) & 1;
    const int jt = tid >> 6;
    const int b  = blockIdx.z;
    const int i0 = blockIdx.y * TI;
    int j = blockIdx.x * 4 + jt;
    const bool jvalid = (j < 126);
    if (!jvalid) j = 125;

    h2 wh[3][3][4];
#pragma unroll
    for (int di = 0; di < 3; ++di)
#pragma unroll
        for (int dj = 0; dj < 3; ++dj)
#pragma unroll
            for (int q = 0; q < 4; ++q) {
                int p = di * 3 + dj;
                float a = Wt[(p * 16 + ch * 8 + 2 * q) * 32 + f];
                float c = Wt[(p * 16 + ch * 8 + 2 * q + 1) * 32 + f];
                wh[di][dj][q] = pkrtz(a, c);
            }

    const float* xb = x + ((size_t)b * 128 * 128 + (size_t)j) * 16 + ch * 8;
    float* op = out + (((size_t)b * 126 + i0) * 126 + j) * 32 + f;

    const _Float16 HINF = (_Float16)__builtin_huge_valf();
    h2 accB = {HINF, HINF};
    h2 accC = {HINF, HINF};

#pragma unroll 2
    for (int r = 0; r < TI + 2; ++r) {
        const float* xr = xb + (size_t)(i0 + r) * 2048;
        h2 hx[12];
#pragma unroll
        for (int dj = 0; dj < 3; ++dj) {
            float4 lo = *reinterpret_cast<const float4*>(xr + dj * 16);
            float4 hi = *reinterpret_cast<const float4*>(xr + dj * 16 + 4);
            hx[dj * 4 + 0] = pkrtz(lo.x, lo.y);
            hx[dj * 4 + 1] = pkrtz(lo.z, lo.w);
            hx[dj * 4 + 2] = pkrtz(hi.x, hi.y);
            hx[dj * 4 + 3] = pkrtz(hi.z, hi.w);
        }

        h2 n0 = rowmin(hx, wh[0]);
        h2 n1 = rowmin(hx, wh[1]);
        h2 n2 = rowmin(hx, wh[2]);

        h2 fin2 = hmin2(accC, n2);
        accC = hmin2(accB, n1);
        accB = n0;

        if (r >= 2) {
            _Float16 vm = fin2[0] < fin2[1] ? fin2[0] : fin2[1];
            float v = (float)vm;
            v = fminf(v, __shfl_xor(v, 32));
            if (jvalid && ch == 0)
                op[(size_t)(r - 2) * (126 * 32)] = v;
        }
    }
}

extern "C" void kernel_launch(void* const* d_in, const int* in_sizes, int n_in,
                              void* d_out, int out_size, void* d_ws, size_t ws_size,
                              hipStream_t stream) {
    const float* x  = (const float*)d_in[0];  // 16*128*128*16
    const float* Wt = (const float*)d_in[1];  // 3*3*16*32
    float* out = (float*)d_out;               // 16*126*126*32

    const size_t xelems = (size_t)16 * 128 * 128 * 16;  // 4,194,304
    dim3 grid(32, 6, 16);
    dim3 block(256);

    if (ws_size >= xelems * sizeof(_Float16)) {
        _Float16* xh = (_Float16*)d_ws;
        cvt_kernel<<<dim3(xelems / (256 * 8)), block, 0, stream>>>(x, xh);
        erosion_h_kernel<<<grid, block, 0, stream>>>(xh, Wt, out);
    } else {
        erosion_kernel<<<grid, block, 0, stream>>>(x, Wt, out);
    }
}